// Round 17
// baseline (200.910 us; speedup 1.0000x reference)
//
#include <hip/hip_runtime.h>

typedef unsigned short u16;
typedef unsigned int u32;
typedef __bf16 bf16x8 __attribute__((ext_vector_type(8)));
typedef float f32x4 __attribute__((ext_vector_type(4)));
typedef u16 u16x8 __attribute__((ext_vector_type(8)));
typedef u16 u16x2 __attribute__((ext_vector_type(2)));

__device__ __forceinline__ float bf2f(u16 u) {
    union { u32 u; float f; } c; c.u = ((u32)u) << 16; return c.f;
}
__device__ __forceinline__ u16 f2bf(float f) {
    union { float f; u32 u; } c; c.f = f;
    u32 r = c.u + 0x7fffu + ((c.u >> 16) & 1u);
    return (u16)(r >> 16);
}
__device__ __forceinline__ u16 f2bfn(float f) {      // native cast -> v_cvt_pk_bf16_f32
    union { __bf16 h; u16 u; } c; c.h = (__bf16)f; return c.u;
}
__device__ __forceinline__ bf16x8 ld_frag(const u16* p) {
    return *reinterpret_cast<const bf16x8*>(p);
}

// ---------------- K0: weight transpose (fp32->bf16) + gather tables ----------------
__global__ __launch_bounds__(256) void k_wT(
    const float* __restrict__ qkv_w, const float* __restrict__ proj_w,
    const float* __restrict__ fc1_w, const float* __restrict__ fc2_w,
    u16* __restrict__ qkvT, u16* __restrict__ projT,
    u16* __restrict__ fc1T, u16* __restrict__ fc2T,
    u32* __restrict__ tok2src, u32* __restrict__ nat2win)
{
    int t = blockIdx.x * 256 + threadIdx.x;          // < 100352
    if (t < 49152) { int k = t / 384, n = t % 384; qkvT[n*128 + k] = f2bf(qkv_w[t]); }
    if (t < 16384) { int k = t / 128, n = t % 128; projT[n*128 + k] = f2bf(proj_w[t]); }
    if (t < 65536) { int k = t / 512, n = t % 512; fc1T[n*128 + k] = f2bf(fc1_w[t]); }
    if (t < 65536) { int k = t / 128, n = t % 128; fc2T[n*512 + k] = f2bf(fc2_w[t]); }
    if (t < 100352) {
        // window-token id t -> natural token index (LN1 shift-gather)
        int wi = t / 98, n = t % 98;
        int iw = wi & 7, ih = (wi >> 3) & 7, id = (wi >> 6) & 3, bb = wi >> 8;
        int tw = n % 7, tt = n / 7, th = tt % 7, td = tt / 7;
        int d  = (id * 2 + td + 1) & 7;
        int hh = ih * 7 + th + 3; if (hh >= 56) hh -= 56;
        int ww = iw * 7 + tw + 3; if (ww >= 56) ww -= 56;
        tok2src[t] = (u32)(((bb * 8 + d) * 56 + hh) * 56 + ww);
        // natural token id t -> window-token row (reverse gather)
        int ww2 = t % 56; int t1 = t / 56;
        int hh2 = t1 % 56; int t2 = t1 / 56;
        int dd = t2 & 7, bb2 = t2 >> 3;
        int d2 = (dd + 7) & 7;
        int hs = hh2 - 3; if (hs < 0) hs += 56;
        int ws_ = ww2 - 3; if (ws_ < 0) ws_ += 56;
        int idd = d2 >> 1, tdd = d2 & 1;
        int ih2 = hs / 7, th2 = hs % 7;
        int iw2 = ws_ / 7, tw2 = ws_ % 7;
        int wi2 = ((bb2*4 + idd)*8 + ih2)*8 + iw2;
        int n2  = (tdd*7 + th2)*7 + tw2;
        nat2win[t] = (u32)(wi2*98 + n2);
    }
}

// ---------------- K1: LN1 + shift-gather (table) + window partition ----------------
__global__ __launch_bounds__(256) void k_ln1_part(
    const float* __restrict__ x, const float* __restrict__ w, const float* __restrict__ b,
    const u32* __restrict__ tok2src, u16* __restrict__ xw)
{
    int wv = threadIdx.x >> 6, l = threadIdx.x & 63;
    int g = blockIdx.x * 4 + wv;                      // < 100352
    long src = (long)tok2src[g] * 128;
    float2 v = *(const float2*)(x + src + l * 2);
    float f0 = v.x, f1 = v.y;
    float s = f0 + f1, s2 = f0*f0 + f1*f1;
    #pragma unroll
    for (int o = 32; o; o >>= 1) { s += __shfl_xor(s, o); s2 += __shfl_xor(s2, o); }
    float mean = s * (1.f/128.f);
    float var  = s2 * (1.f/128.f) - mean*mean;
    float rstd = rsqrtf(var + 1e-5f);
    float y0 = (f0 - mean) * rstd * w[l*2]   + b[l*2];
    float y1 = (f1 - mean) * rstd * w[l*2+1] + b[l*2+1];
    u16x2 o2; o2[0] = f2bf(y0); o2[1] = f2bf(y1);
    *(u16x2*)(xw + (long)g * 128 + l * 2) = o2;
}

// ---------------- K2/K4: GEMM  C[M,N] = A[M,128] @ BT[N,128]^T + bias ----------------
__global__ __launch_bounds__(256) void k_gemm128(
    const u16* __restrict__ A, const u16* __restrict__ BT,
    const float* __restrict__ bias, u16* __restrict__ out, int ldo)
{
    __shared__ __align__(16) u16 la[128*136];
    __shared__ __align__(16) u16 lb[128*136];
    int m0 = blockIdx.x * 128, n0 = blockIdx.y * 128;
    int t = threadIdx.x;
    #pragma unroll
    for (int i = 0; i < 8; i++) {
        int u = t + i * 256;
        int r = u >> 4, c = u & 15;
        *(u16x8*)&la[r*136 + c*8] = *(const u16x8*)&A [(long)(m0 + r)*128 + c*8];
        *(u16x8*)&lb[r*136 + c*8] = *(const u16x8*)&BT[(long)(n0 + r)*128 + c*8];
    }
    __syncthreads();
    int wv = t >> 6, l = t & 63;
    int wm = (wv & 1) * 64, wn = (wv >> 1) * 64;
    int lr = l & 15, lk = (l >> 4) * 8;
    f32x4 acc[4][4] = {};
    #pragma unroll
    for (int kk = 0; kk < 4; kk++) {
        bf16x8 af[4], bfr[4];
        #pragma unroll
        for (int mi = 0; mi < 4; mi++) af[mi]  = ld_frag(&la[(wm + mi*16 + lr)*136 + kk*32 + lk]);
        #pragma unroll
        for (int ni = 0; ni < 4; ni++) bfr[ni] = ld_frag(&lb[(wn + ni*16 + lr)*136 + kk*32 + lk]);
        #pragma unroll
        for (int mi = 0; mi < 4; mi++)
            #pragma unroll
            for (int ni = 0; ni < 4; ni++)
                acc[mi][ni] = __builtin_amdgcn_mfma_f32_16x16x32_bf16(af[mi], bfr[ni], acc[mi][ni], 0, 0, 0);
    }
    int rb = (l >> 4) * 4;
    #pragma unroll
    for (int mi = 0; mi < 4; mi++)
        #pragma unroll
        for (int ni = 0; ni < 4; ni++) {
            int col = n0 + wn + ni*16 + lr;
            float bv = bias[col];
            #pragma unroll
            for (int r = 0; r < 4; r++) {
                int row = m0 + wm + mi*16 + rb + r;
                out[(long)row*ldo + col] = f2bf(acc[mi][ni][r] + bv);
            }
        }
}

// ---------------- K3: attention per (window, head) — register-resident scores (r3) ----------------
__global__ __launch_bounds__(256) void k_attn(
    const u16* __restrict__ qkv, u16* __restrict__ attn_out)
{
    __shared__ __align__(16) u16 lq[128*40];     // [row][k]  (rows >=98 zero)
    __shared__ __align__(16) u16 lk[128*40];     // [row][k]
    __shared__ __align__(16) u16 lvt[32*136];    // [ch][key] (keys >=98 zero)
    __shared__ __align__(16) u16 lp[4][16*136];  // per-wave P tile [row][key]
    int wi = blockIdx.x, h = blockIdx.y;
    int t = threadIdx.x;
    int wv = t >> 6, l = t & 63;
    const long base = (long)wi * 98 * 384 + h * 32;
    u16* lpw = lp[wv];
    // zero this wave's P buffer (cols 112..127 must stay zero for PV chunk 3)
    {
        u16x8 z8 = {};
        for (int i = l; i < 272; i += 64) *(u16x8*)&lpw[i*8] = z8;
    }
    // stage q,k (zero-padded rows)
    #pragma unroll
    for (int i = 0; i < 4; i++) {
        int u = t + i * 256;                  // < 1024
        int mat = u >> 9, row = (u >> 2) & 127, ch = u & 3;
        u16x8 v = {};
        if (row < 98) v = *(const u16x8*)&qkv[base + (long)row*384 + mat*128 + ch*8];
        u16* dst = mat ? lk : lq;
        *(u16x8*)&dst[row*40 + ch*8] = v;
    }
    // stage v transposed: lvt[ch][key], keys 98..127 zero
    #pragma unroll
    for (int i = 0; i < 2; i++) {
        int u = t + i * 256;                  // < 512
        int row = u >> 2, ch = u & 3;
        u16x8 v = {};
        if (row < 98) v = *(const u16x8*)&qkv[base + (long)row*384 + 256 + ch*8];
        #pragma unroll
        for (int j = 0; j < 8; j++) lvt[(ch*8 + j)*136 + row] = v[j];
    }
    __syncthreads();
    int lr = l & 15, lg = l >> 4, lkk = lg * 8;
    const float scale = 0.17677669529663687f;
    for (int rt = wv; rt < 7; rt += 4) {
        bf16x8 qa = ld_frag(&lq[(rt*16 + lr)*40 + lkk]);
        f32x4 s[7];
        #pragma unroll
        for (int ct = 0; ct < 7; ct++) {
            bf16x8 kb = ld_frag(&lk[(ct*16 + lr)*40 + lkk]);
            f32x4 zz = {0.f, 0.f, 0.f, 0.f};
            s[ct] = __builtin_amdgcn_mfma_f32_16x16x32_bf16(qa, kb, zz, 0, 0, 0);
        }
        #pragma unroll
        for (int ct = 0; ct < 7; ct++) {
            bool valid = (ct < 6) || (lr < 2);
            #pragma unroll
            for (int r = 0; r < 4; r++)
                s[ct][r] = valid ? s[ct][r] * scale : -1e30f;
        }
        f32x4 mx;
        #pragma unroll
        for (int r = 0; r < 4; r++) {
            float m = s[0][r];
            #pragma unroll
            for (int ct = 1; ct < 7; ct++) m = fmaxf(m, s[ct][r]);
            #pragma unroll
            for (int o = 1; o < 16; o <<= 1) m = fmaxf(m, __shfl_xor(m, o));
            mx[r] = m;
        }
        f32x4 sum = {0.f, 0.f, 0.f, 0.f};
        #pragma unroll
        for (int ct = 0; ct < 7; ct++)
            #pragma unroll
            for (int r = 0; r < 4; r++) {
                s[ct][r] = __expf(s[ct][r] - mx[r]);
                sum[r] += s[ct][r];
            }
        #pragma unroll
        for (int r = 0; r < 4; r++) {
            float ss = sum[r];
            #pragma unroll
            for (int o = 1; o < 16; o <<= 1) ss += __shfl_xor(ss, o);
            sum[r] = 1.f / ss;
        }
        #pragma unroll
        for (int ct = 0; ct < 7; ct++)
            #pragma unroll
            for (int r = 0; r < 4; r++)
                lpw[(lg*4 + r)*136 + ct*16 + lr] = f2bf(s[ct][r] * sum[r]);
        #pragma unroll
        for (int ni = 0; ni < 2; ni++) {
            f32x4 acc = {0.f, 0.f, 0.f, 0.f};
            #pragma unroll
            for (int kk = 0; kk < 4; kk++) {
                bf16x8 pa = ld_frag(&lpw[lr*136 + kk*32 + lkk]);
                bf16x8 vb = ld_frag(&lvt[(ni*16 + lr)*136 + kk*32 + lkk]);
                acc = __builtin_amdgcn_mfma_f32_16x16x32_bf16(pa, vb, acc, 0, 0, 0);
            }
            #pragma unroll
            for (int r = 0; r < 4; r++) {
                int row = rt*16 + lg*4 + r;
                if (row < 98)
                    attn_out[((long)wi*98 + row)*128 + h*32 + ni*16 + lr] = f2bf(acc[r]);
            }
        }
    }
}

// ---------------- K6: fused res+LN2+MLP (r10 structure + table gather);
// x1 recomputed in epilogue from L2-hot pout/x instead of spilled to global.
__global__ __launch_bounds__(256, 4) void k_mlp2(
    const u16* __restrict__ pout, const float* __restrict__ x,
    const float* __restrict__ w2, const float* __restrict__ b2n,
    const u16* __restrict__ fc1T, const float* __restrict__ b1,
    const u16* __restrict__ fc2T, const float* __restrict__ b2,
    const u32* __restrict__ nat2win,
    float* __restrict__ out)
{
    __shared__ __align__(16) u16 lh [64*136];      // h2 = LN2(x1) (bf16)
    __shared__ __align__(16) u16 lhc[2][64*72];    // hidden chunk, double-buffered, swizzled
    int m0 = blockIdx.x * 64;
    int t = threadIdx.x;
    int wv = t >> 6, l = t & 63;
    int lr = l & 15, lg = l >> 4, lk = lg * 8;
    // ---- staging: 4 iterations; each 16-lane group (lg) handles one row, 8 ch/lane ----
    {
        float4 w2a = *(const float4*)&w2 [lr*8];
        float4 w2b = *(const float4*)&w2 [lr*8 + 4];
        float4 b2a = *(const float4*)&b2n[lr*8];
        float4 b2b = *(const float4*)&b2n[lr*8 + 4];
        float w2v[8] = {w2a.x,w2a.y,w2a.z,w2a.w,w2b.x,w2b.y,w2b.z,w2b.w};
        float b2v[8] = {b2a.x,b2a.y,b2a.z,b2a.w,b2b.x,b2b.y,b2b.z,b2b.w};
        for (int it = 0; it < 4; it++) {
            int row = wv*16 + it*4 + lg;
            int g = m0 + row;                       // natural token id
            long prow = (long)nat2win[g] * 128;
            u16x8 pv = *(const u16x8*)&pout[prow + lr*8];
            float4 xa = *(const float4*)&x[(long)g*128 + lr*8];
            float4 xb = *(const float4*)&x[(long)g*128 + lr*8 + 4];
            float v[8];
            v[0] = bf2f(pv[0]) + xa.x; v[1] = bf2f(pv[1]) + xa.y;
            v[2] = bf2f(pv[2]) + xa.z; v[3] = bf2f(pv[3]) + xa.w;
            v[4] = bf2f(pv[4]) + xb.x; v[5] = bf2f(pv[5]) + xb.y;
            v[6] = bf2f(pv[6]) + xb.z; v[7] = bf2f(pv[7]) + xb.w;
            float s = 0.f, s2 = 0.f;
            #pragma unroll
            for (int j = 0; j < 8; j++) { s += v[j]; s2 += v[j]*v[j]; }
            #pragma unroll
            for (int o = 1; o < 16; o <<= 1) { s += __shfl_xor(s, o); s2 += __shfl_xor(s2, o); }
            float mean = s * (1.f/128.f), var = s2 * (1.f/128.f) - mean*mean;
            float rstd = rsqrtf(var + 1e-5f);
            u16x8 ho;
            #pragma unroll
            for (int j = 0; j < 8; j++)
                ho[j] = f2bfn((v[j] - mean)*rstd*w2v[j] + b2v[j]);
            *(u16x8*)&lh[row*136 + lr*8] = ho;
        }
    }
    __syncthreads();
    // ---- mlp body ----
    f32x4 oacc[4][2] = {};                   // out cols wv*32 + nt*16 + lr
    for (int ch = 0; ch < 8; ch++) {
        char* lc = (char*)lhc[ch & 1];
        int un0 = ch*64 + wv*16;
        bf16x8 bfr[4];
        #pragma unroll
        for (int kk = 0; kk < 4; kk++)
            bfr[kk] = ld_frag(&fc1T[(un0 + lr)*128 + kk*32 + lk]);
        float bv = b1[un0 + lr];
        #pragma unroll
        for (int mt = 0; mt < 4; mt++) {
            f32x4 acc = {0.f, 0.f, 0.f, 0.f};
            #pragma unroll
            for (int kk = 0; kk < 4; kk++) {
                bf16x8 a = ld_frag(&lh[(mt*16 + lr)*136 + kk*32 + lk]);
                acc = __builtin_amdgcn_mfma_f32_16x16x32_bf16(a, bfr[kk], acc, 0, 0, 0);
            }
            #pragma unroll
            for (int r = 0; r < 4; r++) {
                int row = mt*16 + lg*4 + r;
                float vv = acc[r] + bv;
                vv = __fdividef(vv, 1.f + __expf(-vv));      // fast silu
                int byo = row*144 + ((((wv*16 + lr)*2)) ^ ((row & 8) << 2));
                *(u16*)(lc + byo) = f2bfn(vv);
            }
        }
        __syncthreads();                     // chunk ready; also protects buf reuse
        #pragma unroll
        for (int nt = 0; nt < 2; nt++) {
            int col = wv*32 + nt*16 + lr;
            bf16x8 b0 = ld_frag(&fc2T[(long)col*512 + ch*64 + lk]);
            bf16x8 b1f = ld_frag(&fc2T[(long)col*512 + ch*64 + 32 + lk]);
            #pragma unroll
            for (int mt = 0; mt < 4; mt++) {
                int rr = mt*16 + lr;
                int xw_ = (rr & 8) << 2;
                bf16x8 a0 = *(const bf16x8*)(lc + rr*144 + ((lg*16)      ^ xw_));
                bf16x8 a1 = *(const bf16x8*)(lc + rr*144 + ((lg*16 + 64) ^ xw_));
                oacc[mt][nt] = __builtin_amdgcn_mfma_f32_16x16x32_bf16(a0, b0, oacc[mt][nt], 0, 0, 0);
                oacc[mt][nt] = __builtin_amdgcn_mfma_f32_16x16x32_bf16(a1, b1f, oacc[mt][nt], 0, 0, 0);
            }
        }
    }
    // epilogue: += b2 + x1 recomputed from L2-hot pout/x (no spill round-trip)
    #pragma unroll
    for (int nt = 0; nt < 2; nt++) {
        int col = wv*32 + nt*16 + lr;
        float bv = b2[col];
        #pragma unroll
        for (int mt = 0; mt < 4; mt++) {
            #pragma unroll
            for (int r = 0; r < 4; r++) {
                int row = mt*16 + lg*4 + r;
                int g = m0 + row;
                long prow = (long)nat2win[g] * 128;
                float x1v = bf2f(pout[prow + col]) + x[(long)g*128 + col];
                out[(long)g*128 + col] = oacc[mt][nt][r] + bv + x1v;
            }
        }
    }
}

extern "C" void kernel_launch(void* const* d_in, const int* in_sizes, int n_in,
                              void* d_out, int out_size, void* d_ws, size_t ws_size,
                              hipStream_t stream)
{
    const float* x      = (const float*)d_in[0];
    const float* n1w    = (const float*)d_in[1];
    const float* n1b    = (const float*)d_in[2];
    const float* qkv_w  = (const float*)d_in[3];
    const float* qkv_b  = (const float*)d_in[4];
    const float* proj_w = (const float*)d_in[5];
    const float* proj_b = (const float*)d_in[6];
    const float* n2w    = (const float*)d_in[7];
    const float* n2b    = (const float*)d_in[8];
    const float* fc1_w  = (const float*)d_in[9];
    const float* fc1_b  = (const float*)d_in[10];
    const float* fc2_w  = (const float*)d_in[11];
    const float* fc2_b  = (const float*)d_in[12];
    float* out = (float*)d_out;

    u16* ws16  = (u16*)d_ws;
    u16* xw    = ws16;                        // 12,845,056 u16 (ln1 out -> attn_out)
    u16* qkv   = xw + 12845056;               // 38,535,168 u16 (qkv -> proj_out)
    u16* qkvT  = qkv + 38535168;              // 49,152
    u16* projT = qkvT + 49152;                // 16,384
    u16* fc1T  = projT + 16384;               // 65,536
    u16* fc2T  = fc1T + 65536;                // 65,536
    u32* tok2src = (u32*)(fc2T + 65536);      // 100,352 u32
    u32* nat2win = tok2src + 100352;          // 100,352 u32

    k_wT<<<392, 256, 0, stream>>>(qkv_w, proj_w, fc1_w, fc2_w, qkvT, projT, fc1T, fc2T,
                                  tok2src, nat2win);
    k_ln1_part<<<25088, 256, 0, stream>>>(x, n1w, n1b, tok2src, xw);
    dim3 gq(784, 3);
    k_gemm128<<<gq, 256, 0, stream>>>(xw, qkvT, qkv_b, qkv, 384);
    dim3 ga(1024, 4);
    k_attn<<<ga, 256, 0, stream>>>(qkv, xw);                        // attn_out -> xw region
    dim3 gp(784, 1);
    k_gemm128<<<gp, 256, 0, stream>>>(xw, projT, proj_b, qkv, 128); // proj_out -> qkv region
    k_mlp2<<<1568, 256, 0, stream>>>(qkv /*pout*/, x, n2w, n2b,
                                     fc1T, fc1_b, fc2T, fc2_b, nat2win, out);
}

// Round 18
// 192.605 us; speedup vs baseline: 1.0431x; 1.0431x over previous
//
#include <hip/hip_runtime.h>

typedef unsigned short u16;
typedef unsigned int u32;
typedef __bf16 bf16x8 __attribute__((ext_vector_type(8)));
typedef float f32x4 __attribute__((ext_vector_type(4)));
typedef u16 u16x8 __attribute__((ext_vector_type(8)));
typedef u16 u16x2 __attribute__((ext_vector_type(2)));

__device__ __forceinline__ float bf2f(u16 u) {
    union { u32 u; float f; } c; c.u = ((u32)u) << 16; return c.f;
}
__device__ __forceinline__ u16 f2bf(float f) {
    union { float f; u32 u; } c; c.f = f;
    u32 r = c.u + 0x7fffu + ((c.u >> 16) & 1u);
    return (u16)(r >> 16);
}
__device__ __forceinline__ u16 f2bfn(float f) {      // native cast -> v_cvt_pk_bf16_f32
    union { __bf16 h; u16 u; } c; c.h = (__bf16)f; return c.u;
}
__device__ __forceinline__ bf16x8 ld_frag(const u16* p) {
    return *reinterpret_cast<const bf16x8*>(p);
}

// ---------------- K0: weight transpose (fp32->bf16) + gather tables ----------------
__global__ __launch_bounds__(256) void k_wT(
    const float* __restrict__ qkv_w, const float* __restrict__ proj_w,
    const float* __restrict__ fc1_w, const float* __restrict__ fc2_w,
    u16* __restrict__ qkvT, u16* __restrict__ projT,
    u16* __restrict__ fc1T, u16* __restrict__ fc2T,
    u32* __restrict__ tok2src, u32* __restrict__ nat2win)
{
    int t = blockIdx.x * 256 + threadIdx.x;          // < 100352
    if (t < 49152) { int k = t / 384, n = t % 384; qkvT[n*128 + k] = f2bf(qkv_w[t]); }
    if (t < 16384) { int k = t / 128, n = t % 128; projT[n*128 + k] = f2bf(proj_w[t]); }
    if (t < 65536) { int k = t / 512, n = t % 512; fc1T[n*128 + k] = f2bf(fc1_w[t]); }
    if (t < 65536) { int k = t / 128, n = t % 128; fc2T[n*512 + k] = f2bf(fc2_w[t]); }
    if (t < 100352) {
        // window-token id t -> natural token index (LN1 shift-gather)
        int wi = t / 98, n = t % 98;
        int iw = wi & 7, ih = (wi >> 3) & 7, id = (wi >> 6) & 3, bb = wi >> 8;
        int tw = n % 7, tt = n / 7, th = tt % 7, td = tt / 7;
        int d  = (id * 2 + td + 1) & 7;
        int hh = ih * 7 + th + 3; if (hh >= 56) hh -= 56;
        int ww = iw * 7 + tw + 3; if (ww >= 56) ww -= 56;
        tok2src[t] = (u32)(((bb * 8 + d) * 56 + hh) * 56 + ww);
        // natural token id t -> window-token row (reverse gather)
        int ww2 = t % 56; int t1 = t / 56;
        int hh2 = t1 % 56; int t2 = t1 / 56;
        int dd = t2 & 7, bb2 = t2 >> 3;
        int d2 = (dd + 7) & 7;
        int hs = hh2 - 3; if (hs < 0) hs += 56;
        int ws_ = ww2 - 3; if (ws_ < 0) ws_ += 56;
        int idd = d2 >> 1, tdd = d2 & 1;
        int ih2 = hs / 7, th2 = hs % 7;
        int iw2 = ws_ / 7, tw2 = ws_ % 7;
        int wi2 = ((bb2*4 + idd)*8 + ih2)*8 + iw2;
        int n2  = (tdd*7 + th2)*7 + tw2;
        nat2win[t] = (u32)(wi2*98 + n2);
    }
}

// ---------------- K1: LN1 + shift-gather (table) + window partition ----------------
__global__ __launch_bounds__(256) void k_ln1_part(
    const float* __restrict__ x, const float* __restrict__ w, const float* __restrict__ b,
    const u32* __restrict__ tok2src, u16* __restrict__ xw)
{
    int wv = threadIdx.x >> 6, l = threadIdx.x & 63;
    int g = blockIdx.x * 4 + wv;                      // < 100352
    long src = (long)tok2src[g] * 128;
    float2 v = *(const float2*)(x + src + l * 2);
    float f0 = v.x, f1 = v.y;
    float s = f0 + f1, s2 = f0*f0 + f1*f1;
    #pragma unroll
    for (int o = 32; o; o >>= 1) { s += __shfl_xor(s, o); s2 += __shfl_xor(s2, o); }
    float mean = s * (1.f/128.f);
    float var  = s2 * (1.f/128.f) - mean*mean;
    float rstd = rsqrtf(var + 1e-5f);
    float y0 = (f0 - mean) * rstd * w[l*2]   + b[l*2];
    float y1 = (f1 - mean) * rstd * w[l*2+1] + b[l*2+1];
    u16x2 o2; o2[0] = f2bf(y0); o2[1] = f2bf(y1);
    *(u16x2*)(xw + (long)g * 128 + l * 2) = o2;
}

// ---------------- K2/K4: GEMM  C[M,N] = A[M,128] @ BT[N,128]^T + bias ----------------
__global__ __launch_bounds__(256) void k_gemm128(
    const u16* __restrict__ A, const u16* __restrict__ BT,
    const float* __restrict__ bias, u16* __restrict__ out, int ldo)
{
    __shared__ __align__(16) u16 la[128*136];
    __shared__ __align__(16) u16 lb[128*136];
    int m0 = blockIdx.x * 128, n0 = blockIdx.y * 128;
    int t = threadIdx.x;
    #pragma unroll
    for (int i = 0; i < 8; i++) {
        int u = t + i * 256;
        int r = u >> 4, c = u & 15;
        *(u16x8*)&la[r*136 + c*8] = *(const u16x8*)&A [(long)(m0 + r)*128 + c*8];
        *(u16x8*)&lb[r*136 + c*8] = *(const u16x8*)&BT[(long)(n0 + r)*128 + c*8];
    }
    __syncthreads();
    int wv = t >> 6, l = t & 63;
    int wm = (wv & 1) * 64, wn = (wv >> 1) * 64;
    int lr = l & 15, lk = (l >> 4) * 8;
    f32x4 acc[4][4] = {};
    #pragma unroll
    for (int kk = 0; kk < 4; kk++) {
        bf16x8 af[4], bfr[4];
        #pragma unroll
        for (int mi = 0; mi < 4; mi++) af[mi]  = ld_frag(&la[(wm + mi*16 + lr)*136 + kk*32 + lk]);
        #pragma unroll
        for (int ni = 0; ni < 4; ni++) bfr[ni] = ld_frag(&lb[(wn + ni*16 + lr)*136 + kk*32 + lk]);
        #pragma unroll
        for (int mi = 0; mi < 4; mi++)
            #pragma unroll
            for (int ni = 0; ni < 4; ni++)
                acc[mi][ni] = __builtin_amdgcn_mfma_f32_16x16x32_bf16(af[mi], bfr[ni], acc[mi][ni], 0, 0, 0);
    }
    int rb = (l >> 4) * 4;
    #pragma unroll
    for (int mi = 0; mi < 4; mi++)
        #pragma unroll
        for (int ni = 0; ni < 4; ni++) {
            int col = n0 + wn + ni*16 + lr;
            float bv = bias[col];
            #pragma unroll
            for (int r = 0; r < 4; r++) {
                int row = m0 + wm + mi*16 + rb + r;
                out[(long)row*ldo + col] = f2bf(acc[mi][ni][r] + bv);
            }
        }
}

// ---------------- K3: attention per (window, head) — register-resident scores (r3) ----------------
__global__ __launch_bounds__(256) void k_attn(
    const u16* __restrict__ qkv, u16* __restrict__ attn_out)
{
    __shared__ __align__(16) u16 lq[128*40];     // [row][k]  (rows >=98 zero)
    __shared__ __align__(16) u16 lk[128*40];     // [row][k]
    __shared__ __align__(16) u16 lvt[32*136];    // [ch][key] (keys >=98 zero)
    __shared__ __align__(16) u16 lp[4][16*136];  // per-wave P tile [row][key]
    int wi = blockIdx.x, h = blockIdx.y;
    int t = threadIdx.x;
    int wv = t >> 6, l = t & 63;
    const long base = (long)wi * 98 * 384 + h * 32;
    u16* lpw = lp[wv];
    // zero this wave's P buffer (cols 112..127 must stay zero for PV chunk 3)
    {
        u16x8 z8 = {};
        for (int i = l; i < 272; i += 64) *(u16x8*)&lpw[i*8] = z8;
    }
    // stage q,k (zero-padded rows)
    #pragma unroll
    for (int i = 0; i < 4; i++) {
        int u = t + i * 256;                  // < 1024
        int mat = u >> 9, row = (u >> 2) & 127, ch = u & 3;
        u16x8 v = {};
        if (row < 98) v = *(const u16x8*)&qkv[base + (long)row*384 + mat*128 + ch*8];
        u16* dst = mat ? lk : lq;
        *(u16x8*)&dst[row*40 + ch*8] = v;
    }
    // stage v transposed: lvt[ch][key], keys 98..127 zero
    #pragma unroll
    for (int i = 0; i < 2; i++) {
        int u = t + i * 256;                  // < 512
        int row = u >> 2, ch = u & 3;
        u16x8 v = {};
        if (row < 98) v = *(const u16x8*)&qkv[base + (long)row*384 + 256 + ch*8];
        #pragma unroll
        for (int j = 0; j < 8; j++) lvt[(ch*8 + j)*136 + row] = v[j];
    }
    __syncthreads();
    int lr = l & 15, lg = l >> 4, lkk = lg * 8;
    const float scale = 0.17677669529663687f;
    for (int rt = wv; rt < 7; rt += 4) {
        bf16x8 qa = ld_frag(&lq[(rt*16 + lr)*40 + lkk]);
        f32x4 s[7];
        #pragma unroll
        for (int ct = 0; ct < 7; ct++) {
            bf16x8 kb = ld_frag(&lk[(ct*16 + lr)*40 + lkk]);
            f32x4 zz = {0.f, 0.f, 0.f, 0.f};
            s[ct] = __builtin_amdgcn_mfma_f32_16x16x32_bf16(qa, kb, zz, 0, 0, 0);
        }
        #pragma unroll
        for (int ct = 0; ct < 7; ct++) {
            bool valid = (ct < 6) || (lr < 2);
            #pragma unroll
            for (int r = 0; r < 4; r++)
                s[ct][r] = valid ? s[ct][r] * scale : -1e30f;
        }
        f32x4 mx;
        #pragma unroll
        for (int r = 0; r < 4; r++) {
            float m = s[0][r];
            #pragma unroll
            for (int ct = 1; ct < 7; ct++) m = fmaxf(m, s[ct][r]);
            #pragma unroll
            for (int o = 1; o < 16; o <<= 1) m = fmaxf(m, __shfl_xor(m, o));
            mx[r] = m;
        }
        f32x4 sum = {0.f, 0.f, 0.f, 0.f};
        #pragma unroll
        for (int ct = 0; ct < 7; ct++)
            #pragma unroll
            for (int r = 0; r < 4; r++) {
                s[ct][r] = __expf(s[ct][r] - mx[r]);
                sum[r] += s[ct][r];
            }
        #pragma unroll
        for (int r = 0; r < 4; r++) {
            float ss = sum[r];
            #pragma unroll
            for (int o = 1; o < 16; o <<= 1) ss += __shfl_xor(ss, o);
            sum[r] = 1.f / ss;
        }
        #pragma unroll
        for (int ct = 0; ct < 7; ct++)
            #pragma unroll
            for (int r = 0; r < 4; r++)
                lpw[(lg*4 + r)*136 + ct*16 + lr] = f2bf(s[ct][r] * sum[r]);
        #pragma unroll
        for (int ni = 0; ni < 2; ni++) {
            f32x4 acc = {0.f, 0.f, 0.f, 0.f};
            #pragma unroll
            for (int kk = 0; kk < 4; kk++) {
                bf16x8 pa = ld_frag(&lpw[lr*136 + kk*32 + lkk]);
                bf16x8 vb = ld_frag(&lvt[(ni*16 + lr)*136 + kk*32 + lkk]);
                acc = __builtin_amdgcn_mfma_f32_16x16x32_bf16(pa, vb, acc, 0, 0, 0);
            }
            #pragma unroll
            for (int r = 0; r < 4; r++) {
                int row = rt*16 + lg*4 + r;
                if (row < 98)
                    attn_out[((long)wi*98 + row)*128 + h*32 + ni*16 + lr] = f2bf(acc[r]);
            }
        }
    }
}

// ---------------- K6: fused res+LN2+MLP (r10 structure) + table gather ----------------
__global__ __launch_bounds__(256, 4) void k_mlp2(
    const u16* __restrict__ pout, const float* __restrict__ x,
    const float* __restrict__ w2, const float* __restrict__ b2n,
    const u16* __restrict__ fc1T, const float* __restrict__ b1,
    const u16* __restrict__ fc2T, const float* __restrict__ b2,
    const u32* __restrict__ nat2win,
    u16* __restrict__ x1g, float* __restrict__ out)
{
    __shared__ __align__(16) u16 lh [64*136];      // h2 = LN2(x1) (bf16)
    __shared__ __align__(16) u16 lhc[2][64*72];    // hidden chunk, double-buffered, swizzled
    int m0 = blockIdx.x * 64;
    int t = threadIdx.x;
    int wv = t >> 6, l = t & 63;
    int lr = l & 15, lg = l >> 4, lk = lg * 8;
    // ---- staging: 4 iterations; each 16-lane group (lg) handles one row, 8 ch/lane ----
    {
        float4 w2a = *(const float4*)&w2 [lr*8];
        float4 w2b = *(const float4*)&w2 [lr*8 + 4];
        float4 b2a = *(const float4*)&b2n[lr*8];
        float4 b2b = *(const float4*)&b2n[lr*8 + 4];
        float w2v[8] = {w2a.x,w2a.y,w2a.z,w2a.w,w2b.x,w2b.y,w2b.z,w2b.w};
        float b2v[8] = {b2a.x,b2a.y,b2a.z,b2a.w,b2b.x,b2b.y,b2b.z,b2b.w};
        for (int it = 0; it < 4; it++) {
            int row = wv*16 + it*4 + lg;
            int g = m0 + row;                       // natural token id
            long prow = (long)nat2win[g] * 128;
            u16x8 pv = *(const u16x8*)&pout[prow + lr*8];
            float4 xa = *(const float4*)&x[(long)g*128 + lr*8];
            float4 xb = *(const float4*)&x[(long)g*128 + lr*8 + 4];
            float v[8];
            v[0] = bf2f(pv[0]) + xa.x; v[1] = bf2f(pv[1]) + xa.y;
            v[2] = bf2f(pv[2]) + xa.z; v[3] = bf2f(pv[3]) + xa.w;
            v[4] = bf2f(pv[4]) + xb.x; v[5] = bf2f(pv[5]) + xb.y;
            v[6] = bf2f(pv[6]) + xb.z; v[7] = bf2f(pv[7]) + xb.w;
            float s = 0.f, s2 = 0.f;
            #pragma unroll
            for (int j = 0; j < 8; j++) { s += v[j]; s2 += v[j]*v[j]; }
            #pragma unroll
            for (int o = 1; o < 16; o <<= 1) { s += __shfl_xor(s, o); s2 += __shfl_xor(s2, o); }
            float mean = s * (1.f/128.f), var = s2 * (1.f/128.f) - mean*mean;
            float rstd = rsqrtf(var + 1e-5f);
            u16x8 xo, ho;
            #pragma unroll
            for (int j = 0; j < 8; j++) {
                xo[j] = f2bfn(v[j]);
                ho[j] = f2bfn((v[j] - mean)*rstd*w2v[j] + b2v[j]);
            }
            *(u16x8*)&x1g[(long)g*128 + lr*8] = xo;    // x1 -> global (L2-resident)
            *(u16x8*)&lh [row*136 + lr*8] = ho;
        }
    }
    __syncthreads();
    // ---- mlp body ----
    f32x4 oacc[4][2] = {};                   // out cols wv*32 + nt*16 + lr
    for (int ch = 0; ch < 8; ch++) {
        char* lc = (char*)lhc[ch & 1];
        int un0 = ch*64 + wv*16;
        bf16x8 bfr[4];
        #pragma unroll
        for (int kk = 0; kk < 4; kk++)
            bfr[kk] = ld_frag(&fc1T[(un0 + lr)*128 + kk*32 + lk]);
        float bv = b1[un0 + lr];
        #pragma unroll
        for (int mt = 0; mt < 4; mt++) {
            f32x4 acc = {0.f, 0.f, 0.f, 0.f};
            #pragma unroll
            for (int kk = 0; kk < 4; kk++) {
                bf16x8 a = ld_frag(&lh[(mt*16 + lr)*136 + kk*32 + lk]);
                acc = __builtin_amdgcn_mfma_f32_16x16x32_bf16(a, bfr[kk], acc, 0, 0, 0);
            }
            #pragma unroll
            for (int r = 0; r < 4; r++) {
                int row = mt*16 + lg*4 + r;
                float vv = acc[r] + bv;
                vv = __fdividef(vv, 1.f + __expf(-vv));      // fast silu
                int byo = row*144 + ((((wv*16 + lr)*2)) ^ ((row & 8) << 2));
                *(u16*)(lc + byo) = f2bfn(vv);
            }
        }
        __syncthreads();                     // chunk ready; also protects buf reuse
        #pragma unroll
        for (int nt = 0; nt < 2; nt++) {
            int col = wv*32 + nt*16 + lr;
            bf16x8 b0 = ld_frag(&fc2T[(long)col*512 + ch*64 + lk]);
            bf16x8 b1f = ld_frag(&fc2T[(long)col*512 + ch*64 + 32 + lk]);
            #pragma unroll
            for (int mt = 0; mt < 4; mt++) {
                int rr = mt*16 + lr;
                int xw_ = (rr & 8) << 2;
                bf16x8 a0 = *(const bf16x8*)(lc + rr*144 + ((lg*16)      ^ xw_));
                bf16x8 a1 = *(const bf16x8*)(lc + rr*144 + ((lg*16 + 64) ^ xw_));
                oacc[mt][nt] = __builtin_amdgcn_mfma_f32_16x16x32_bf16(a0, b0, oacc[mt][nt], 0, 0, 0);
                oacc[mt][nt] = __builtin_amdgcn_mfma_f32_16x16x32_bf16(a1, b1f, oacc[mt][nt], 0, 0, 0);
            }
        }
    }
    // epilogue: += b2 + x1(global, L2-hot), write fp32
    #pragma unroll
    for (int nt = 0; nt < 2; nt++) {
        int col = wv*32 + nt*16 + lr;
        float bv = b2[col];
        #pragma unroll
        for (int mt = 0; mt < 4; mt++) {
            #pragma unroll
            for (int r = 0; r < 4; r++) {
                int row = mt*16 + lg*4 + r;
                out[(long)(m0 + row)*128 + col] =
                    oacc[mt][nt][r] + bv + bf2f(x1g[(long)(m0 + row)*128 + col]);
            }
        }
    }
}

extern "C" void kernel_launch(void* const* d_in, const int* in_sizes, int n_in,
                              void* d_out, int out_size, void* d_ws, size_t ws_size,
                              hipStream_t stream)
{
    const float* x      = (const float*)d_in[0];
    const float* n1w    = (const float*)d_in[1];
    const float* n1b    = (const float*)d_in[2];
    const float* qkv_w  = (const float*)d_in[3];
    const float* qkv_b  = (const float*)d_in[4];
    const float* proj_w = (const float*)d_in[5];
    const float* proj_b = (const float*)d_in[6];
    const float* n2w    = (const float*)d_in[7];
    const float* n2b    = (const float*)d_in[8];
    const float* fc1_w  = (const float*)d_in[9];
    const float* fc1_b  = (const float*)d_in[10];
    const float* fc2_w  = (const float*)d_in[11];
    const float* fc2_b  = (const float*)d_in[12];
    float* out = (float*)d_out;

    u16* ws16  = (u16*)d_ws;
    u16* xw    = ws16;                        // 12,845,056 u16 (ln1 out -> attn_out -> x1 spill)
    u16* qkv   = xw + 12845056;               // 38,535,168 u16 (qkv -> proj_out)
    u16* qkvT  = qkv + 38535168;              // 49,152
    u16* projT = qkvT + 49152;                // 16,384
    u16* fc1T  = projT + 16384;               // 65,536
    u16* fc2T  = fc1T + 65536;                // 65,536
    u32* tok2src = (u32*)(fc2T + 65536);      // 100,352 u32
    u32* nat2win = tok2src + 100352;          // 100,352 u32

    k_wT<<<392, 256, 0, stream>>>(qkv_w, proj_w, fc1_w, fc2_w, qkvT, projT, fc1T, fc2T,
                                  tok2src, nat2win);
    k_ln1_part<<<25088, 256, 0, stream>>>(x, n1w, n1b, tok2src, xw);
    dim3 gq(784, 3);
    k_gemm128<<<gq, 256, 0, stream>>>(xw, qkvT, qkv_b, qkv, 384);
    dim3 ga(1024, 4);
    k_attn<<<ga, 256, 0, stream>>>(qkv, xw);                        // attn_out -> xw region
    dim3 gp(784, 1);
    k_gemm128<<<gp, 256, 0, stream>>>(xw, projT, proj_b, qkv, 128); // proj_out -> qkv region
    k_mlp2<<<1568, 256, 0, stream>>>(qkv /*pout*/, x, n2w, n2b,
                                     fc1T, fc1_b, fc2T, fc2_b, nat2win,
                                     xw /*x1 spill (attn_out is dead)*/, out);
}